// Round 4
// baseline (293.621 us; speedup 1.0000x reference)
//
#include <hip/hip_runtime.h>
#include <hip/hip_bf16.h>

#define NN 16384
#define EE 128

typedef __attribute__((ext_vector_type(8))) short bf16x8;   // 8 bf16 = 4 VGPRs (MFMA A/B frag)
typedef __attribute__((ext_vector_type(4))) float f32x4;    // MFMA C/D frag
typedef __attribute__((ext_vector_type(4))) float f4;

static __device__ inline short f2bf(float f) {
    __hip_bfloat16 h = __float2bfloat16(f);
    return *reinterpret_cast<short*>(&h);
}

// ---------------------------------------------------------------------------
// pack_a: A [16384][128] fp32 -> Apk fragment-packed bf16.
// Apk[(m16*4+ks)*64 + lane][j] = bf16( A[m16*16 + (lane&15)][ks*32 + (lane>>4)*8 + j] )
// (lane&15 -> index, (lane>>4)*8+j -> k : identical structure for the mfma
//  a-slot and b-slot, so this frag can be fed to either operand.)
// ---------------------------------------------------------------------------
__global__ __launch_bounds__(256) void pack_a(const float* __restrict__ A,
                                              bf16x8* __restrict__ out) {
    int lane = threadIdx.x & 63;
    int unit = blockIdx.x * 4 + (threadIdx.x >> 6);   // 0..4095
    int m16 = unit >> 2, ks = unit & 3;
    int row = m16 * 16 + (lane & 15);
    int k0  = ks * 32 + (lane >> 4) * 8;
    const float* src = A + (size_t)row * EE + k0;
    f4 v0 = *reinterpret_cast<const f4*>(src);
    f4 v1 = *reinterpret_cast<const f4*>(src + 4);
    bf16x8 r;
    r[0] = f2bf(v0[0]); r[1] = f2bf(v0[1]); r[2] = f2bf(v0[2]); r[3] = f2bf(v0[3]);
    r[4] = f2bf(v1[0]); r[5] = f2bf(v1[1]); r[6] = f2bf(v1[2]); r[7] = f2bf(v1[3]);
    out[(size_t)unit * 64 + lane] = r;
}

// ---------------------------------------------------------------------------
// pack_b: B [128][16384] fp32, W[128] -> Bpk = bf16(W[k]*B[k][n]), same frag
// structure (lane&15 -> n, (lane>>4)*8+j -> k).
// ---------------------------------------------------------------------------
__global__ __launch_bounds__(256) void pack_b(const float* __restrict__ B,
                                              const float* __restrict__ W,
                                              bf16x8* __restrict__ out) {
    int lane = threadIdx.x & 63;
    int unit = blockIdx.x * 4 + (threadIdx.x >> 6);   // 0..4095
    int n16 = unit >> 2, ks = unit & 3;
    int n  = n16 * 16 + (lane & 15);
    int k0 = ks * 32 + (lane >> 4) * 8;
    bf16x8 r;
#pragma unroll
    for (int j = 0; j < 8; ++j) {
        int k = k0 + j;
        r[j] = f2bf(W[k] * B[(size_t)k * NN + n]);
    }
    out[(size_t)unit * 64 + lane] = r;
}

// ---------------------------------------------------------------------------
// gemm_pk: C = A x (W.B). One block = 128x128 tile, 4 waves (2x2), each wave
// 64x64 = 4x4 frags of 16x16x32, K = 4 steps of 32.
// SWAPPED operands: D = mfma(a_slot=Bpk[n], b_slot=Apk[m]) gives
//   D[R][Cc] = sum_k W.B[k][n0+R] * A[m0+Cc][k] = G[m0+Cc][n0+R]
// with D layout col=lane&15 (our m), row=(lane>>4)*4+reg (our n): each thread
// holds 4 CONSECUTIVE columns of one C row -> direct float4 store. No LDS,
// no transpose, no barriers.
// ---------------------------------------------------------------------------
__global__ __launch_bounds__(256, 4) void gemm_pk(const bf16x8* __restrict__ Apk,
                                                  const bf16x8* __restrict__ Bpk,
                                                  float* __restrict__ C) {
    // XCD chunking + bn-FAST supertile walk: resident blocks per XCD cover
    // ~2 bm x 64 bn -> they write dense 256-row x 32KB bands of C (DRAM page
    // locality), and share the A panel (L2-resident).
    int bid = blockIdx.x;
    int swz = (bid & 7) * 2048 + (bid >> 3);
    int st  = swz >> 11;            // supertile 0..7 (4 rows x 2 cols)
    int r   = swz & 2047;
    int bm  = (st >> 1) * 32 + (r >> 6);    // bn-fast within supertile
    int bn  = (st & 1) * 64 + (r & 63);

    int lane = threadIdx.x & 63;
    int wid  = threadIdx.x >> 6;
    int wr   = wid >> 1, wc = wid & 1;
    int m16_0 = bm * 8 + wr * 4;
    int n16_0 = bn * 8 + wc * 4;

    f32x4 acc[4][4];
#pragma unroll
    for (int m = 0; m < 4; ++m)
#pragma unroll
        for (int n = 0; n < 4; ++n)
            acc[m][n] = (f32x4){0.f, 0.f, 0.f, 0.f};

#pragma unroll
    for (int ks = 0; ks < 4; ++ks) {
        bf16x8 a[4], b[4];
#pragma unroll
        for (int m = 0; m < 4; ++m)
            a[m] = Apk[(size_t)((m16_0 + m) * 4 + ks) * 64 + lane];
#pragma unroll
        for (int n = 0; n < 4; ++n)
            b[n] = Bpk[(size_t)((n16_0 + n) * 4 + ks) * 64 + lane];
#pragma unroll
        for (int m = 0; m < 4; ++m)
#pragma unroll
            for (int n = 0; n < 4; ++n)  // swapped operand order (see header)
                acc[m][n] = __builtin_amdgcn_mfma_f32_16x16x32_bf16(b[n], a[m], acc[m][n], 0, 0, 0);
    }

    // ---- epilogue: direct float4 stores (no LDS) ----
    // thread owns: row = m0 + (lane&15), cols n0 + (lane>>4)*4 + {0..3}
    int l15 = lane & 15, rg = lane >> 4;
    int growb = bm * 128 + wr * 64 + l15;        // + m*16
    int gcolb = bn * 128 + wc * 64 + rg * 4;     // + n*16
#pragma unroll
    for (int m = 0; m < 4; ++m) {
        size_t rowoff = (size_t)(growb + m * 16) * NN;
#pragma unroll
        for (int n = 0; n < 4; ++n)
            *reinterpret_cast<f4*>(&C[rowoff + gcolb + n * 16]) = acc[m][n];
    }
}

// ---------------------------------------------------------------------------
// Fallback (only if ws_size < 8 MB): plain fp32, correct but slow.
// ---------------------------------------------------------------------------
__global__ __launch_bounds__(64) void gemm_fb(const float* __restrict__ A,
                                              const float* __restrict__ B,
                                              const float* __restrict__ W,
                                              float* __restrict__ C) {
    int col = blockIdx.x * 64 + threadIdx.x;
    int row = blockIdx.y;
    float s = 0.f;
#pragma unroll 8
    for (int k = 0; k < EE; ++k)
        s = fmaf(A[(size_t)row * EE + k] * W[k], B[(size_t)k * NN + col], s);
    C[(size_t)row * NN + col] = s;
}

extern "C" void kernel_launch(void* const* d_in, const int* in_sizes, int n_in,
                              void* d_out, int out_size, void* d_ws, size_t ws_size,
                              hipStream_t stream) {
    const float* A = (const float*)d_in[0];   // DV2_H        [16384,128]
    const float* B = (const float*)d_in[1];   // invDE_HT_DV2 [128,16384]
    const float* W = (const float*)d_in[2];   // W            [128]
    float* C = (float*)d_out;                 // G            [16384,16384] fp32

    const size_t need = (size_t)2 * 4096 * 64 * sizeof(bf16x8);  // 8 MB
    if (ws_size >= need) {
        bf16x8* Apk = (bf16x8*)d_ws;
        bf16x8* Bpk = Apk + (size_t)4096 * 64;
        pack_a<<<1024, 256, 0, stream>>>(A, Apk);
        pack_b<<<1024, 256, 0, stream>>>(B, W, Bpk);
        gemm_pk<<<16384, 256, 0, stream>>>(Apk, Bpk, C);
    } else {
        dim3 g(NN / 64, NN);
        gemm_fb<<<g, 64, 0, stream>>>(A, B, W, C);
    }
}

// Round 5
// 282.215 us; speedup vs baseline: 1.0404x; 1.0404x over previous
//
#include <hip/hip_runtime.h>
#include <hip/hip_bf16.h>

#define NN 16384
#define EE 128

typedef __attribute__((ext_vector_type(8))) short bf16x8;   // 8 bf16 = 4 VGPRs (MFMA A/B frag)
typedef __attribute__((ext_vector_type(4))) float f32x4;    // MFMA C/D frag
typedef __attribute__((ext_vector_type(4))) float f4;

static __device__ inline short f2bf(float f) {
    __hip_bfloat16 h = __float2bfloat16(f);
    return *reinterpret_cast<short*>(&h);
}

// ---------------------------------------------------------------------------
// pack_a: A [16384][128] fp32 -> Apk fragment-packed bf16 (mfma A layout).
// ---------------------------------------------------------------------------
__global__ __launch_bounds__(256) void pack_a(const float* __restrict__ A,
                                              bf16x8* __restrict__ out) {
    int lane = threadIdx.x & 63;
    int unit = blockIdx.x * 4 + (threadIdx.x >> 6);   // 0..4095
    int m16 = unit >> 2, ks = unit & 3;
    int row = m16 * 16 + (lane & 15);
    int k0  = ks * 32 + (lane >> 4) * 8;
    const float* src = A + (size_t)row * EE + k0;
    f4 v0 = *reinterpret_cast<const f4*>(src);
    f4 v1 = *reinterpret_cast<const f4*>(src + 4);
    bf16x8 r;
    r[0] = f2bf(v0[0]); r[1] = f2bf(v0[1]); r[2] = f2bf(v0[2]); r[3] = f2bf(v0[3]);
    r[4] = f2bf(v1[0]); r[5] = f2bf(v1[1]); r[6] = f2bf(v1[2]); r[7] = f2bf(v1[3]);
    out[(size_t)unit * 64 + lane] = r;
}

// ---------------------------------------------------------------------------
// pack_b: B [128][16384] fp32, W[128] -> Bpk = bf16(W[k]*B[k][n]) (mfma B layout).
// ---------------------------------------------------------------------------
__global__ __launch_bounds__(256) void pack_b(const float* __restrict__ B,
                                              const float* __restrict__ W,
                                              bf16x8* __restrict__ out) {
    int lane = threadIdx.x & 63;
    int unit = blockIdx.x * 4 + (threadIdx.x >> 6);   // 0..4095
    int n16 = unit >> 2, ks = unit & 3;
    int n  = n16 * 16 + (lane & 15);
    int k0 = ks * 32 + (lane >> 4) * 8;
    bf16x8 r;
#pragma unroll
    for (int j = 0; j < 8; ++j) {
        int k = k0 + j;
        r[j] = f2bf(W[k] * B[(size_t)k * NN + n]);
    }
    out[(size_t)unit * 64 + lane] = r;
}

// ---------------------------------------------------------------------------
// gemm_pk: identical compute + epilogue to R3 (LDS chunked transpose, float4
// row stores, 16 KB LDS, 4 blocks/CU). ONLY the block->tile walk changed:
// plain bn-fast per-XCD bands. XCD c owns C rows [c*2048, (c+1)*2048) and
// walks them bn-fastest: co-resident blocks share one bm stripe (A panel
// 64 KB, L2-hot) and fill one 128-row band of C near-linearly -- adjacent
// blocks write adjacent 512B chunks of the SAME DRAM pages concurrently.
// ---------------------------------------------------------------------------
__global__ __launch_bounds__(256, 4) void gemm_pk(const bf16x8* __restrict__ Apk,
                                                  const bf16x8* __restrict__ Bpk,
                                                  float* __restrict__ C) {
    int bid   = blockIdx.x;
    int xcd   = bid & 7;            // dispatch round-robins XCDs
    int local = bid >> 3;           // 0..2047 within this XCD's chunk
    int bm    = xcd * 16 + (local >> 7);   // 16 bm-stripes per XCD band
    int bn    = local & 127;               // bn-fastest

    int lane = threadIdx.x & 63;
    int wid  = threadIdx.x >> 6;
    int wr   = wid >> 1, wc = wid & 1;
    int m16_0 = bm * 8 + wr * 4;
    int n16_0 = bn * 8 + wc * 4;

    f32x4 acc[4][4];
#pragma unroll
    for (int m = 0; m < 4; ++m)
#pragma unroll
        for (int n = 0; n < 4; ++n)
            acc[m][n] = (f32x4){0.f, 0.f, 0.f, 0.f};

#pragma unroll
    for (int ks = 0; ks < 4; ++ks) {
        bf16x8 a[4], b[4];
#pragma unroll
        for (int m = 0; m < 4; ++m)
            a[m] = Apk[(size_t)((m16_0 + m) * 4 + ks) * 64 + lane];
#pragma unroll
        for (int n = 0; n < 4; ++n)
            b[n] = Bpk[(size_t)((n16_0 + n) * 4 + ks) * 64 + lane];
#pragma unroll
        for (int m = 0; m < 4; ++m)
#pragma unroll
            for (int n = 0; n < 4; ++n)
                acc[m][n] = __builtin_amdgcn_mfma_f32_16x16x32_bf16(a[m], b[n], acc[m][n], 0, 0, 0);
    }

    // ---- epilogue: chunked transpose (16 rows / 4 KB per wave at a time) ----
    // MFMA C/D frag layout: col = lane&15, row = (lane>>4)*4 + reg  [m89/m91]
    __shared__ float cst[4 * 16 * 64];          // 16 KB total, 4 KB per wave
    float* wl = cst + wid * (16 * 64);

    int rg  = lane >> 4;                         // lane group 0..3
    int l15 = lane & 15;
    int gr0 = bm * 128 + wr * 64;
    int gc0 = bn * 128 + wc * 64 + (l15 << 2);

#pragma unroll
    for (int m = 0; m < 4; ++m) {
        // write: rows rl = rg*4+ri; swizzle keyed (rl>>2)&1 = rg&1 -> 2-way (free)
        int swW = (rg & 1) << 4;
#pragma unroll
        for (int ri = 0; ri < 4; ++ri) {
            int rl = rg * 4 + ri;
#pragma unroll
            for (int n = 0; n < 4; ++n)
                wl[rl * 64 + ((n * 16 + l15) ^ swW)] = acc[m][n][ri];
        }
        // read back float4 rows; rl = r4*4 + rg, swizzle key (rl>>2)&1 = r4&1
#pragma unroll
        for (int r4 = 0; r4 < 4; ++r4) {
            int rl = r4 * 4 + rg;
            int swR = (r4 & 1) << 4;
            f4 v = *reinterpret_cast<const f4*>(&wl[rl * 64 + (((l15 << 2)) ^ swR)]);
            *reinterpret_cast<f4*>(&C[(size_t)(gr0 + m * 16 + rl) * NN + gc0]) = v;
        }
        // next m reuses the same 4 KB chunk; wave-private -> no barrier.
    }
}

// ---------------------------------------------------------------------------
// Fallback (only if ws_size < 8 MB): plain fp32, correct but slow.
// ---------------------------------------------------------------------------
__global__ __launch_bounds__(64) void gemm_fb(const float* __restrict__ A,
                                              const float* __restrict__ B,
                                              const float* __restrict__ W,
                                              float* __restrict__ C) {
    int col = blockIdx.x * 64 + threadIdx.x;
    int row = blockIdx.y;
    float s = 0.f;
#pragma unroll 8
    for (int k = 0; k < EE; ++k)
        s = fmaf(A[(size_t)row * EE + k] * W[k], B[(size_t)k * NN + col], s);
    C[(size_t)row * NN + col] = s;
}

extern "C" void kernel_launch(void* const* d_in, const int* in_sizes, int n_in,
                              void* d_out, int out_size, void* d_ws, size_t ws_size,
                              hipStream_t stream) {
    const float* A = (const float*)d_in[0];   // DV2_H        [16384,128]
    const float* B = (const float*)d_in[1];   // invDE_HT_DV2 [128,16384]
    const float* W = (const float*)d_in[2];   // W            [128]
    float* C = (float*)d_out;                 // G            [16384,16384] fp32

    const size_t need = (size_t)2 * 4096 * 64 * sizeof(bf16x8);  // 8 MB
    if (ws_size >= need) {
        bf16x8* Apk = (bf16x8*)d_ws;
        bf16x8* Bpk = Apk + (size_t)4096 * 64;
        pack_a<<<1024, 256, 0, stream>>>(A, Apk);
        pack_b<<<1024, 256, 0, stream>>>(B, W, Bpk);
        gemm_pk<<<16384, 256, 0, stream>>>(Apk, Bpk, C);
    } else {
        dim3 g(NN / 64, NN);
        gemm_fb<<<g, 64, 0, stream>>>(A, B, W, C);
    }
}

// Round 6
// 257.689 us; speedup vs baseline: 1.1394x; 1.0952x over previous
//
#include <hip/hip_runtime.h>
#include <hip/hip_bf16.h>

#define NN 16384
#define EE 128

typedef __attribute__((ext_vector_type(8))) short bf16x8;   // 8 bf16 = 4 VGPRs (MFMA A/B frag)
typedef __attribute__((ext_vector_type(4))) float f32x4;    // MFMA C/D frag
typedef __attribute__((ext_vector_type(4))) float f4;

static __device__ inline short f2bf(float f) {
    __hip_bfloat16 h = __float2bfloat16(f);
    return *reinterpret_cast<short*>(&h);
}

// ---------------------------------------------------------------------------
// pack_a: A [16384][128] fp32 -> Apk fragment-packed bf16 (mfma operand layout:
// lane&15 -> index, (lane>>4)*8+j -> k; feedable to either mfma slot).
// ---------------------------------------------------------------------------
__global__ __launch_bounds__(256) void pack_a(const float* __restrict__ A,
                                              bf16x8* __restrict__ out) {
    int lane = threadIdx.x & 63;
    int unit = blockIdx.x * 4 + (threadIdx.x >> 6);   // 0..4095
    int m16 = unit >> 2, ks = unit & 3;
    int row = m16 * 16 + (lane & 15);
    int k0  = ks * 32 + (lane >> 4) * 8;
    const float* src = A + (size_t)row * EE + k0;
    f4 v0 = *reinterpret_cast<const f4*>(src);
    f4 v1 = *reinterpret_cast<const f4*>(src + 4);
    bf16x8 r;
    r[0] = f2bf(v0[0]); r[1] = f2bf(v0[1]); r[2] = f2bf(v0[2]); r[3] = f2bf(v0[3]);
    r[4] = f2bf(v1[0]); r[5] = f2bf(v1[1]); r[6] = f2bf(v1[2]); r[7] = f2bf(v1[3]);
    out[(size_t)unit * 64 + lane] = r;
}

// ---------------------------------------------------------------------------
// pack_b: B [128][16384] fp32, W[128] -> Bpk = bf16(W[k]*B[k][n]), same layout.
// ---------------------------------------------------------------------------
__global__ __launch_bounds__(256) void pack_b(const float* __restrict__ B,
                                              const float* __restrict__ W,
                                              bf16x8* __restrict__ out) {
    int lane = threadIdx.x & 63;
    int unit = blockIdx.x * 4 + (threadIdx.x >> 6);   // 0..4095
    int n16 = unit >> 2, ks = unit & 3;
    int n  = n16 * 16 + (lane & 15);
    int k0 = ks * 32 + (lane >> 4) * 8;
    bf16x8 r;
#pragma unroll
    for (int j = 0; j < 8; ++j) {
        int k = k0 + j;
        r[j] = f2bf(W[k] * B[(size_t)k * NN + n]);
    }
    out[(size_t)unit * 64 + lane] = r;
}

// ---------------------------------------------------------------------------
// gemm_pk: R3 structure (bm-fast supertile walk, 16 KB chunked-LDS epilogue,
// occupancy 4) with ONE change: swapped-operand MFMA (R4-verified math) makes
// each thread's f32x4 row-contiguous, so the LDS transpose uses ds_write_b128
// (4/m-band) instead of 16x ds_write_b32. LDS ops/wave: 80 -> 32.
//   D = mfma(a_slot=Bpk[n], b_slot=Apk[m]):
//     thread owns C row m*16 + (lane&15), cols n*16 + (lane>>4)*4 + {0..3}.
// ---------------------------------------------------------------------------
__global__ __launch_bounds__(256, 4) void gemm_pk(const bf16x8* __restrict__ Apk,
                                                  const bf16x8* __restrict__ Bpk,
                                                  float* __restrict__ C) {
    // R3 walk: XCD chunking + bm-fast supertile (best measured: 265 us total).
    int bid = blockIdx.x;
    int swz = (bid & 7) * 2048 + (bid >> 3);
    int st  = swz >> 11;            // supertile 0..7 (4 rows x 2 cols)
    int r   = swz & 2047;
    int bm  = (st >> 1) * 32 + (r & 31);
    int bn  = (st & 1) * 64 + (r >> 5);

    int lane = threadIdx.x & 63;
    int wid  = threadIdx.x >> 6;
    int wr   = wid >> 1, wc = wid & 1;
    int m16_0 = bm * 8 + wr * 4;
    int n16_0 = bn * 8 + wc * 4;

    f32x4 acc[4][4];
#pragma unroll
    for (int m = 0; m < 4; ++m)
#pragma unroll
        for (int n = 0; n < 4; ++n)
            acc[m][n] = (f32x4){0.f, 0.f, 0.f, 0.f};

#pragma unroll
    for (int ks = 0; ks < 4; ++ks) {
        bf16x8 a[4], b[4];
#pragma unroll
        for (int m = 0; m < 4; ++m)
            a[m] = Apk[(size_t)((m16_0 + m) * 4 + ks) * 64 + lane];
#pragma unroll
        for (int n = 0; n < 4; ++n)
            b[n] = Bpk[(size_t)((n16_0 + n) * 4 + ks) * 64 + lane];
#pragma unroll
        for (int m = 0; m < 4; ++m)
#pragma unroll
            for (int n = 0; n < 4; ++n)  // swapped operands (see header)
                acc[m][n] = __builtin_amdgcn_mfma_f32_16x16x32_bf16(b[n], a[m], acc[m][n], 0, 0, 0);
    }

    // ---- epilogue: chunked transpose, all-b128 LDS ops ----
    // chunk = one m-band: 16 rows x 64 cols fp32 = 4 KB per wave (16 KB/block).
    // T2-style XOR swizzle on the float-col: phys = col ^ ((row&7)<<2)
    // (16B granularity, preserves f4 atomicity, 8 slots per 8-row stripe).
    __shared__ float cst[4 * 16 * 64];          // 16 KB total, 4 KB per wave
    float* wl = cst + wid * (16 * 64);

    int rg  = lane >> 4;                         // lane group 0..3
    int l15 = lane & 15;
    int gr0 = bm * 128 + wr * 64;
    int gc0 = bn * 128 + wc * 64;

#pragma unroll
    for (int m = 0; m < 4; ++m) {
        // write: thread's f4 = row l15, cols n*16+rg*4+{0..3}  -> ds_write_b128
        int swW = (l15 & 7) << 2;
#pragma unroll
        for (int n = 0; n < 4; ++n) {
            int colf = (n * 16 + rg * 4) ^ swW;
            *reinterpret_cast<f4*>(&wl[l15 * 64 + colf]) = acc[m][n];
        }
        // read back: 4 rows x 256 B per instr -> ds_read_b128, then f4 store
#pragma unroll
        for (int r4 = 0; r4 < 4; ++r4) {
            int rl   = r4 * 4 + rg;
            int colf = (l15 * 4) ^ ((rl & 7) << 2);
            f4 v = *reinterpret_cast<const f4*>(&wl[rl * 64 + colf]);
            *reinterpret_cast<f4*>(&C[(size_t)(gr0 + m * 16 + rl) * NN + gc0 + l15 * 4]) = v;
        }
        // next m reuses the same 4 KB chunk; wave-private -> no barrier.
    }
}

// ---------------------------------------------------------------------------
// Fallback (only if ws_size < 8 MB): plain fp32, correct but slow.
// ---------------------------------------------------------------------------
__global__ __launch_bounds__(64) void gemm_fb(const float* __restrict__ A,
                                              const float* __restrict__ B,
                                              const float* __restrict__ W,
                                              float* __restrict__ C) {
    int col = blockIdx.x * 64 + threadIdx.x;
    int row = blockIdx.y;
    float s = 0.f;
#pragma unroll 8
    for (int k = 0; k < EE; ++k)
        s = fmaf(A[(size_t)row * EE + k] * W[k], B[(size_t)k * NN + col], s);
    C[(size_t)row * NN + col] = s;
}

extern "C" void kernel_launch(void* const* d_in, const int* in_sizes, int n_in,
                              void* d_out, int out_size, void* d_ws, size_t ws_size,
                              hipStream_t stream) {
    const float* A = (const float*)d_in[0];   // DV2_H        [16384,128]
    const float* B = (const float*)d_in[1];   // invDE_HT_DV2 [128,16384]
    const float* W = (const float*)d_in[2];   // W            [128]
    float* C = (float*)d_out;                 // G            [16384,16384] fp32

    const size_t need = (size_t)2 * 4096 * 64 * sizeof(bf16x8);  // 8 MB
    if (ws_size >= need) {
        bf16x8* Apk = (bf16x8*)d_ws;
        bf16x8* Bpk = Apk + (size_t)4096 * 64;
        pack_a<<<1024, 256, 0, stream>>>(A, Apk);
        pack_b<<<1024, 256, 0, stream>>>(B, W, Bpk);
        gemm_pk<<<16384, 256, 0, stream>>>(Apk, Bpk, C);
    } else {
        dim3 g(NN / 64, NN);
        gemm_fb<<<g, 64, 0, stream>>>(A, B, W, C);
    }
}